// Round 18
// baseline (44.042 us; speedup 1.0000x reference)
//
#include <hip/hip_runtime.h>
#include <math.h>

// NeRF fused volume renderer, MI355X (gfx950) — MFMA, independent-wave design.
// Round 18: r17 (42.6us best) with block-level hardware refill.
//   r17 counters: grid == residency (8192 waves = 8192 rays, 0 queued blocks)
//   -> occupancy decays as rays finish (49% avg = long drain). Fix: 256-thr
//   blocks (4 waves = 4 rays), grid 2048; LDS 24.6KB -> 6 blocks/CU resident
//   (24 waves/CU) + 512 queued blocks refilled by the command processor as
//   blocks retire. Shorter, flatter drain beats the 32->24 peak-residency loss.
//   Everything else = r17: scalarized wave-uniform setup (rfl -> SGPRs),
//   launch_bounds(.,8) (VGPR cap 64; allocator lands 32 + ~6MB spill, proven
//   faster than clean-72 at half occupancy), wave walks its ray's 8x16-sample
//   tiles sequentially, 6-register carry (f,W,WT,R,G,B), no main-loop barriers.
// Layouts (m89-verified / ISA doc): C/D col=lane&15, row=(lane>>4)*4+reg;
// x32 A/B k=(lane>>4)*8+e; x16 A/B k=(lane>>4)*4+e.

typedef _Float16 f16x8 __attribute__((ext_vector_type(8)));
typedef _Float16 f16x4 __attribute__((ext_vector_type(4)));
typedef float f32x4 __attribute__((ext_vector_type(4)));

static constexpr float STEPf = 0.040594940802395566f; // 3*sqrt(3)/128 in f32

static __device__ __forceinline__ unsigned pk2(float a, float b) {
    return __builtin_bit_cast(unsigned, __builtin_amdgcn_cvt_pkrtz(a, b));
}
static __device__ __forceinline__ f16x8 mk8(unsigned a, unsigned b, unsigned c, unsigned d) {
    uint4 u = make_uint4(a, b, c, d);
    return __builtin_bit_cast(f16x8, u);
}
static __device__ __forceinline__ f16x4 pkh(const f32x4 c) {
    uint2 u;
    u.x = pk2(fmaxf(c[0], 0.f), fmaxf(c[1], 0.f));
    u.y = pk2(fmaxf(c[2], 0.f), fmaxf(c[3], 0.f));
    return __builtin_bit_cast(f16x4, u);
}
// force a wave-uniform f32 into an SGPR
static __device__ __forceinline__ float rfl(float x) {
    return __builtin_bit_cast(float, __builtin_amdgcn_readfirstlane(__builtin_bit_cast(int, x)));
}

extern "C" __global__ void __launch_bounds__(256, 8)
nerf_mfma(const float* __restrict__ rays_o, const float* __restrict__ viewdirs,
          const void* __restrict__ occ,
          const float* __restrict__ W1g, const float* __restrict__ b1g,
          const float* __restrict__ W2g, const float* __restrict__ b2g,
          const float* __restrict__ Wsg, const float* __restrict__ bsg,
          const float* __restrict__ Wcg, const float* __restrict__ Wdg,
          const float* __restrict__ bcg, const float* __restrict__ Wrg,
          const float* __restrict__ brg,
          float* __restrict__ out, int nrays)
{
    __shared__ __align__(16) unsigned char sW1[64 * 64];
    __shared__ __align__(16) unsigned char sW2[64 * 128];
    __shared__ __align__(16) unsigned char sWc[64 * 128];
    __shared__ __align__(16) unsigned char sHC[16 * 128];
    __shared__ __align__(16) float sWs[64];
    __shared__ __align__(16) float sB1[64], sB2[64];
    __shared__ __align__(16) float sPdB[4][64];    // per-wave (pe_d@Wd + bc); same-wave RW
    __shared__ int sKind;

    const int tid = threadIdx.x;   // 0..255

    // ---------------- staging: COALESCED global reads, swizzled LDS writes ----
    for (int idx = tid; idx < 1024; idx += 256)             // zero sW1 (covers k-pad)
        ((uint32_t*)sW1)[idx] = 0u;
    __syncthreads();                                        // pad-zero before scatter
    for (int idx = tid; idx < 27 * 64; idx += 256) {        // W1, linear in memory
        const int k = idx >> 6, h = idx & 63;
        *(_Float16*)(sW1 + h * 64 + (((k >> 3) ^ (h & 3)) << 4) + ((k & 7) << 1)) =
            (_Float16)W1g[idx];
    }
    for (int idx = tid; idx < 64 * 64; idx += 256) {        // W2, Wc, linear
        const int k = idx >> 6, h = idx & 63;
        const int off = h * 128 + ((((k >> 2) ^ ((h & 7) << 1)) << 3)) + ((k & 3) << 1);
        *(_Float16*)(sW2 + off) = (_Float16)W2g[idx];
        *(_Float16*)(sWc + off) = (_Float16)Wcg[idx];
    }
    for (int idx = tid; idx < 192; idx += 256) {            // rgb head rows, linear
        const int kk = idx / 3, c = idx - 3 * kk;
        const _Float16 v = (_Float16)Wrg[idx];
        #pragma unroll
        for (int r = 0; r < 16; ++r) {
            if ((r % 3) == c) {
                const int off = r * 128 + ((((kk >> 2) ^ ((r & 7) << 1)) << 3)) + ((kk & 3) << 1);
                *(_Float16*)(sHC + off) = v;
            }
        }
    }
    if (tid < 64) {
        sB1[tid] = b1g[tid]; sB2[tid] = b2g[tid];
        sWs[tid] = Wsg[tid];
    }
    if (tid == 0) {   // sniff occ dtype: 0=u8, else 32-bit raw (i32/f32 both !=0 test)
        const int*   oi = (const int*)occ;
        const float* of = (const float*)occ;
        bool i32ok = true, f32ok = true;
        for (int k = 0; k < 64; ++k) {
            if (oi[k] != 0 && oi[k] != 1) i32ok = false;
            const float f = of[k];
            if (!(f == 0.f || f == 1.f)) f32ok = false;
        }
        sKind = (i32ok || f32ok) ? 1 : 0;
    }
    __syncthreads();   // the ONLY block-wide barrier

    const int lane = tid & 63;
    const int wid  = tid >> 6;        // 0..3: wave = independent ray
    const int kind = sKind;
    const int lh = lane & 15, g = lane >> 4;
    const int swz8 = (lh & 7) << 1;

    const float bsV = bsg[0];
    const float br0 = brg[0], br1 = brg[1], br2 = brg[2];

    const int ray = __builtin_amdgcn_readfirstlane((int)(blockIdx.x << 2) + wid);
    if (ray >= nrays) return;

    // ---- per-ray setup; uniform scalars end in SGPRs (scalar loads + rfl) ----
    const float ox = rays_o[ray * 3 + 0], oy = rays_o[ray * 3 + 1], oz = rays_o[ray * 3 + 2];
    const float dxv = viewdirs[ray * 3 + 0], dyv = viewdirs[ray * 3 + 1], dzv = viewdirs[ray * 3 + 2];
    float t_near, t_far;
    {
        const float sdx = fabsf(dxv) < 1e-8f ? 1e-8f : dxv;
        const float sdy = fabsf(dyv) < 1e-8f ? 1e-8f : dyv;
        const float sdz = fabsf(dzv) < 1e-8f ? 1e-8f : dzv;
        const float t1x = (-1.5f - ox) / sdx, t2x = (1.5f - ox) / sdx;
        const float t1y = (-1.5f - oy) / sdy, t2y = (1.5f - oy) / sdy;
        const float t1z = (-1.5f - oz) / sdz, t2z = (1.5f - oz) / sdz;
        t_near = rfl(fmaxf(fmaxf(fminf(t1x, t2x), fminf(t1y, t2y)),
                           fmaxf(fminf(t1z, t2z), 0.f)));
        t_far  = rfl(fminf(fminf(fmaxf(t1x, t2x), fmaxf(t1y, t2y)), fmaxf(t1z, t2z)));
    }

    float W = 0.f, WT = 0.f, Rr = 0.f, Gg = 0.f, Bb = 0.f;

    if (t_near < t_far) {
        // dir posenc -> sPdB[wid] (lane j computes feature j; same-wave RW)
        {
            float ped[15];
            ped[0] = dxv; ped[1] = dyv; ped[2] = dzv;
            const float dc[3] = {dxv, dyv, dzv};
            #pragma unroll
            for (int c = 0; c < 3; ++c) {
                float s1, c1;
                __sincosf(dc[c], &s1, &c1);
                ped[3 + c * 4 + 0] = s1;
                ped[3 + c * 4 + 1] = 2.f * s1 * c1;
                ped[3 + c * 4 + 2] = c1;
                ped[3 + c * 4 + 3] = 1.f - 2.f * s1 * s1;
            }
            float pd = 0.f;
            #pragma unroll
            for (int i = 0; i < 15; ++i) pd += ped[i] * Wdg[i * 64 + lane];
            sPdB[wid][lane] = pd + bcg[lane];
        }

        float f = 1.f;
        #pragma unroll 1
        for (int bt = 0; bt < 8; ++bt) {
            const float tS = t_near + ((float)((bt << 4) | lh) + 0.5f) * STEPf;
            const bool in_seg = tS < t_far;
            if (__ballot(in_seg) == 0ULL) break;   // tiles ascend in t: done

            // ---- own-sample validity (occ gather) ----
            bool valid;
            {
                const float px = ox + dxv * tS, py = oy + dyv * tS, pz = oz + dzv * tS;
                const float cx = (px + 1.5f) * (128.f / 3.f);
                const float cy = (py + 1.5f) * (128.f / 3.f);
                const float cz = (pz + 1.5f) * (128.f / 3.f);
                const bool in_box = (cx >= 0.f) & (cx < 128.f) & (cy >= 0.f) & (cy < 128.f)
                                  & (cz >= 0.f) & (cz < 128.f);
                const int ix = min(max((int)floorf(cx), 0), 127);
                const int iy = min(max((int)floorf(cy), 0), 127);
                const int iz = min(max((int)floorf(cz), 0), 127);
                const int ci = (ix << 14) | (iy << 7) | iz;
                const unsigned raw = (kind == 0) ? (unsigned)((const unsigned char*)occ)[ci]
                                                 : ((const unsigned*)occ)[ci];
                valid = in_seg & in_box & (raw != 0u);
            }
            if (__ballot(valid) == 0ULL) continue;  // empty tile: S_tile = 0, f unchanged

            // ---- posenc in x32-B layout: lane -> feats 8g..8g+7 of sample lh ----
            f16x8 bx;
            {
                const float qx = ox + dxv * tS, qy = oy + dyv * tS, qz = oz + dzv * tS;
                const float u = (g < 2) ? qx : ((g == 2) ? qy : qz);
                const float v = (g == 1) ? qy : ((g == 2) ? qz : 0.f);
                float su1, cu1, sv1, cv1;
                __sincosf(u, &su1, &cu1);
                __sincosf(v, &sv1, &cv1);
                const float su2 = 2.f * su1 * cu1, cu2 = 1.f - 2.f * su1 * su1;
                const float su4 = 2.f * su2 * cu2, cu4 = 1.f - 2.f * su2 * su2;
                const float su8 = 2.f * su4 * cu4, cu8 = 1.f - 2.f * su4 * su4;
                const float sv2 = 2.f * sv1 * cv1, cv2 = 1.f - 2.f * sv1 * sv1;
                const float sv4 = 2.f * sv2 * cv2, cv4 = 1.f - 2.f * sv2 * sv2;
                const float sv8 = 2.f * sv4 * cv4;
                const bool g0 = (g == 0);
                const float f0 = g0 ? qx : cu2;
                const float f1 = g0 ? qy : cu4;
                const float f2 = g0 ? qz : cu8;
                const float f3 = g0 ? su1 : sv1;
                const float f4 = g0 ? su2 : sv2;
                const float f5 = g0 ? su4 : sv4;
                const float f6 = g0 ? su8 : sv8;
                const float f7 = g0 ? cu1 : ((g == 3) ? 0.f : cv1);
                bx = mk8(pk2(f0, f1), pk2(f2, f3), pk2(f4, f5), pk2(f6, f7));
            }

            // ---- L1 (16x16x32): bias as C ----
            f16x4 bh1[4];
            #pragma unroll
            for (int mt = 0; mt < 4; ++mt) {
                const f32x4 bf = *(const f32x4*)&sB1[16 * mt + 4 * g];
                const f16x8 a = *(const f16x8*)(sW1 + (16 * mt + lh) * 64 + ((g ^ (lh & 3)) << 4));
                f32x4 c = __builtin_amdgcn_mfma_f32_16x16x32_f16(a, bx, bf, 0, 0, 0);
                bh1[mt] = pkh(c);   // D rows 4g+r == B k 4g+e for k-step mt
            }
            // ---- L2 (4 x 16x16x16) + fused VALU sigma partial ----
            f16x4 bh2[4];
            float sp = 0.f;
            #pragma unroll
            for (int mt = 0; mt < 4; ++mt) {
                const int row = (16 * mt + lh) * 128;
                const f16x4 a0 = *(const f16x4*)(sW2 + row + (((0 + g) ^ swz8) << 3));
                const f16x4 a1 = *(const f16x4*)(sW2 + row + (((4 + g) ^ swz8) << 3));
                const f16x4 a2 = *(const f16x4*)(sW2 + row + (((8 + g) ^ swz8) << 3));
                const f16x4 a3 = *(const f16x4*)(sW2 + row + (((12 + g) ^ swz8) << 3));
                const f32x4 bf = *(const f32x4*)&sB2[16 * mt + 4 * g];
                const f32x4 ws = *(const f32x4*)&sWs[16 * mt + 4 * g];
                f32x4 c = __builtin_amdgcn_mfma_f32_16x16x16f16(a0, bh1[0], bf, 0, 0, 0);
                c = __builtin_amdgcn_mfma_f32_16x16x16f16(a1, bh1[1], c, 0, 0, 0);
                c = __builtin_amdgcn_mfma_f32_16x16x16f16(a2, bh1[2], c, 0, 0, 0);
                c = __builtin_amdgcn_mfma_f32_16x16x16f16(a3, bh1[3], c, 0, 0, 0);
                const float r0 = fmaxf(c[0], 0.f), r1 = fmaxf(c[1], 0.f);
                const float r2 = fmaxf(c[2], 0.f), r3 = fmaxf(c[3], 0.f);
                sp += ws[0] * r0 + ws[1] * r1 + ws[2] * r2 + ws[3] * r3;
                uint2 u; u.x = pk2(r0, r1); u.y = pk2(r2, r3);
                bh2[mt] = __builtin_bit_cast(f16x4, u);
            }
            // ---- Wc layer (C = pd + bc) + FUSED rgb head ----
            f32x4 accC;
            #pragma unroll
            for (int mt = 0; mt < 4; ++mt) {
                const int row = (16 * mt + lh) * 128;
                const f16x4 a0 = *(const f16x4*)(sWc + row + (((0 + g) ^ swz8) << 3));
                const f16x4 a1 = *(const f16x4*)(sWc + row + (((4 + g) ^ swz8) << 3));
                const f16x4 a2 = *(const f16x4*)(sWc + row + (((8 + g) ^ swz8) << 3));
                const f16x4 a3 = *(const f16x4*)(sWc + row + (((12 + g) ^ swz8) << 3));
                const f32x4 pdf = *(const f32x4*)&sPdB[wid][16 * mt + 4 * g];
                const f16x4 aC = *(const f16x4*)(sHC + lh * 128 + (((4 * mt + g) ^ swz8) << 3));
                f32x4 c = __builtin_amdgcn_mfma_f32_16x16x16f16(a0, bh2[0], pdf, 0, 0, 0);
                c = __builtin_amdgcn_mfma_f32_16x16x16f16(a1, bh2[1], c, 0, 0, 0);
                c = __builtin_amdgcn_mfma_f32_16x16x16f16(a2, bh2[2], c, 0, 0, 0);
                c = __builtin_amdgcn_mfma_f32_16x16x16f16(a3, bh2[3], c, 0, 0, 0);
                const f16x4 bgf = pkh(c);
                f32x4 ca = (mt == 0) ? f32x4{0.f, 0.f, 0.f, 0.f} : accC;
                accC = __builtin_amdgcn_mfma_f32_16x16x16f16(aC, bgf, ca, 0, 0, 0);
            }
            // ---- sigma reduce over g-groups (all lanes get full sum) ----
            sp += __shfl_xor(sp, 16);
            sp += __shfl_xor(sp, 32);
            // ---- rgb extraction: row 4g+j has color (g+j)%3 ----
            const float crS = (g == 1) ? accC[2] : (g == 2) ? accC[1] : accC[0];
            const float cgS = (g == 0) ? accC[1] : (g == 1) ? accC[0]
                            : (g == 2) ? accC[2] : accC[1];
            const float cbS = (g == 0) ? accC[2] : (g == 1) ? accC[1]
                            : (g == 2) ? accC[0] : accC[2];

            const float sigma = valid ? fmaxf(sp + bsV, 0.f) : 0.f;
            const float rC = 1.f / (1.f + __expf(-(crS + br0)));
            const float gC = 1.f / (1.f + __expf(-(cgS + br1)));
            const float bC = 1.f / (1.f + __expf(-(cbS + br2)));

            // ---- compositing over this tile (carry via f, exact) ----
            const float sdelta = sigma * STEPf;
            float scan = sdelta;
            #pragma unroll
            for (int off = 1; off < 16; off <<= 1) {
                const float n = __shfl_up(scan, off);
                if (lh >= off) scan += n;
            }
            const float T     = __expf(-(scan - sdelta));
            const float alpha = 1.f - __expf(-sdelta);
            const float w = f * T * alpha;          // tile factor folded per-lane
            W  += w;
            WT += w * tS;
            Rr += w * rC;
            Gg += w * gC;
            Bb += w * bC;
            const float Stile = rfl(__shfl(scan, (lane & 48) | 15));  // tile sigma-sum
            f *= __expf(-Stile);
            if (f < 6e-6f) break;                   // transmittance exhausted
        }
    }

    // ---- ONE reduce over the 16 lh lanes per ray (values g-replicated) ----
    #pragma unroll
    for (int off = 1; off < 16; off <<= 1) {
        W  += __shfl_xor(W,  off);
        WT += __shfl_xor(WT, off);
        Rr += __shfl_xor(Rr, off);
        Gg += __shfl_xor(Gg, off);
        Bb += __shfl_xor(Bb, off);
    }
    if (lane == 0) {
        const float bg_ = 1.f - W;
        out[ray * 3 + 0] = Rr + bg_;
        out[ray * 3 + 1] = Gg + bg_;
        out[ray * 3 + 2] = Bb + bg_;
        out[3 * nrays + ray] = WT;
        out[4 * nrays + ray] = W;
    }
}

extern "C" void kernel_launch(void* const* d_in, const int* in_sizes, int n_in,
                              void* d_out, int out_size, void* d_ws, size_t ws_size,
                              hipStream_t stream) {
    const float* rays_o   = (const float*)d_in[0];
    const float* viewdirs = (const float*)d_in[1];
    const void*  occ      = (const void*) d_in[2];
    const float* W1 = (const float*)d_in[3];
    const float* b1 = (const float*)d_in[4];
    const float* W2 = (const float*)d_in[5];
    const float* b2 = (const float*)d_in[6];
    const float* Ws = (const float*)d_in[7];
    const float* bs = (const float*)d_in[8];
    const float* Wc = (const float*)d_in[9];
    const float* Wd = (const float*)d_in[10];
    const float* bc = (const float*)d_in[11];
    const float* Wr = (const float*)d_in[12];
    const float* br = (const float*)d_in[13];
    float* out = (float*)d_out;

    const int nrays = in_sizes[0] / 3;
    const int nblocks = (nrays + 3) / 4;     // 4 rays (waves) per 256-thread block
                                             // nrays=8192 -> 2048 blocks: 6/CU resident,
                                             // ~512 queued -> HW refill smooths drain

    nerf_mfma<<<nblocks, 256, 0, stream>>>(rays_o, viewdirs, occ,
                                           W1, b1, W2, b2, Ws, bs, Wc, Wd, bc, Wr, br,
                                           out, nrays);
}